// Round 2
// baseline (844.071 us; speedup 1.0000x reference)
//
#include <hip/hip_runtime.h>
#include <hip/hip_bf16.h>
#include <stdint.h>

// R4: 8-phase-style counted-vmcnt schedule on the M2(C) complex GEMM.
// Ring of 4 LDS slice-buffers (32-k each, 128 KB total), steady-state
// s_waitcnt vmcnt(12) (3 slices in flight, never drained in-loop), raw
// s_barrier pairs + sched_barrier(0) fences, setprio(1) around MFMA cluster
// (T3+T4+T5). 512 threads / 8 waves, wave tile 64 rows x {q0,q1}x16 cols so
// the blade decode stays thread-local. Math identical to R3 (absmax-stable).

#define BATCH 2048
#define DIN 2048
#define DD 2048
#define K2 4096   // 2*DIN
#define R2R 4096  // 2*BATCH
#define NSLICE 128  // K2/32

typedef __attribute__((ext_vector_type(8))) __bf16 bf16x8;
typedef __attribute__((ext_vector_type(4))) float f32x4;
typedef __attribute__((ext_vector_type(4))) unsigned int u32x4;

#define NEG 0x80008000u

__device__ __forceinline__ unsigned short f2bf(float f) {
  unsigned int u = __float_as_uint(f);
  u = (u + 0x7FFFu + ((u >> 16) & 1u)) >> 16;  // RNE
  return (unsigned short)u;
}

__device__ __forceinline__ u32x4 pack8(const float* s) {
  u32x4 p;
#pragma unroll
  for (int w = 0; w < 4; ++w)
    p[w] = (unsigned)f2bf(s[2 * w]) | ((unsigned)f2bf(s[2 * w + 1]) << 16);
  return p;
}

__device__ __forceinline__ void gl_lds16(const void* g, void* l) {
  __builtin_amdgcn_global_load_lds((__attribute__((address_space(1))) void*)g,
                                   (__attribute__((address_space(3))) void*)l,
                                   16, 0, 0);
}

union FragU {
  u32x4 u;
  bf16x8 v;
};

// ---------------------------------------------------------------------------
// pack_x: x [8*B, DIN] fp32 -> Ar, Ai [2B, 2*DIN] bf16.  (unchanged from R3)
//   M11=(x0+x3)+i(x7+x4)  M12=(x1-x5)+i(x6-x2)
//   M21=(x1+x5)+i(x6+x2)  M22=(x0-x3)+i(x7-x4)
// Global 1/2 of the inverse transform folded here (exact exponent shift).
__global__ void pack_x(const float* __restrict__ x,
                       unsigned short* __restrict__ Ar,
                       unsigned short* __restrict__ Ai) {
  const int b = blockIdx.x;
  const int l0 = threadIdx.x * 8;
  float v[8][8];
#pragma unroll
  for (int i = 0; i < 8; ++i) {
    const float4* p = (const float4*)&x[((size_t)i * BATCH + b) * DIN + l0];
    float4 a = p[0], c = p[1];
    v[i][0] = a.x; v[i][1] = a.y; v[i][2] = a.z; v[i][3] = a.w;
    v[i][4] = c.x; v[i][5] = c.y; v[i][6] = c.z; v[i][7] = c.w;
  }
  const size_t r0 = (size_t)(2 * b) * K2;
  const size_t r1 = (size_t)(2 * b + 1) * K2;
  float t[8];
#pragma unroll
  for (int e = 0; e < 8; ++e) t[e] = 0.5f * (v[0][e] + v[3][e]);
  *(u32x4*)&Ar[r0 + l0] = pack8(t);
#pragma unroll
  for (int e = 0; e < 8; ++e) t[e] = 0.5f * (v[1][e] - v[5][e]);
  *(u32x4*)&Ar[r0 + DIN + l0] = pack8(t);
#pragma unroll
  for (int e = 0; e < 8; ++e) t[e] = 0.5f * (v[1][e] + v[5][e]);
  *(u32x4*)&Ar[r1 + l0] = pack8(t);
#pragma unroll
  for (int e = 0; e < 8; ++e) t[e] = 0.5f * (v[0][e] - v[3][e]);
  *(u32x4*)&Ar[r1 + DIN + l0] = pack8(t);
#pragma unroll
  for (int e = 0; e < 8; ++e) t[e] = 0.5f * (v[7][e] + v[4][e]);
  *(u32x4*)&Ai[r0 + l0] = pack8(t);
#pragma unroll
  for (int e = 0; e < 8; ++e) t[e] = 0.5f * (v[6][e] - v[2][e]);
  *(u32x4*)&Ai[r0 + DIN + l0] = pack8(t);
#pragma unroll
  for (int e = 0; e < 8; ++e) t[e] = 0.5f * (v[6][e] + v[2][e]);
  *(u32x4*)&Ai[r1 + l0] = pack8(t);
#pragma unroll
  for (int e = 0; e < 8; ++e) t[e] = 0.5f * (v[7][e] - v[4][e]);
  *(u32x4*)&Ai[r1 + l0 + DIN] = pack8(t);
}

// ---------------------------------------------------------------------------
// pack_w: W [DIN, 8*DD] fp32 -> Br, Bi [2*DD, 2*DIN] bf16 (transposed).
// (unchanged from R3)
__constant__ int c_pw[4][2] = {{0, 3}, {1, 5}, {7, 4}, {6, 2}};

__global__ void pack_w(const float* __restrict__ W,
                       unsigned short* __restrict__ Br,
                       unsigned short* __restrict__ Bi) {
  __shared__ float ts[64][65], td[64][65];
  const int z = blockIdx.z;
  const int p0 = c_pw[z][0], p1 = c_pw[z][1];
  unsigned short* dst = (z < 2) ? Br : Bi;
  const int rs = z & 1;
  const int rd = rs ^ 1;
  const int d0 = blockIdx.x * 64;
  const int l0 = blockIdx.y * 64;
  const int tid = threadIdx.x;
  {
    const int row = tid >> 4;
    const int col = (tid & 15) * 4;
#pragma unroll
    for (int j = 0; j < 4; ++j) {
      const size_t base = (size_t)(l0 + row + j * 16) * (8 * DD);
      float4 a = *(const float4*)&W[base + (size_t)p0 * DD + d0 + col];
      float4 b = *(const float4*)&W[base + (size_t)p1 * DD + d0 + col];
      ts[row + j * 16][col + 0] = a.x + b.x;
      ts[row + j * 16][col + 1] = a.y + b.y;
      ts[row + j * 16][col + 2] = a.z + b.z;
      ts[row + j * 16][col + 3] = a.w + b.w;
      td[row + j * 16][col + 0] = a.x - b.x;
      td[row + j * 16][col + 1] = a.y - b.y;
      td[row + j * 16][col + 2] = a.z - b.z;
      td[row + j * 16][col + 3] = a.w - b.w;
    }
  }
  __syncthreads();
  {
    const int rc = (tid & 7) * 8;
    int c = tid >> 3;
#pragma unroll
    for (int h = 0; h < 2; ++h, c += 32) {
      float s[8], dl[8];
#pragma unroll
      for (int w = 0; w < 8; ++w) {
        s[w] = ts[rc + w][c];
        dl[w] = td[rc + w][c];
      }
      *(u32x4*)&dst[(size_t)(d0 + c) * K2 + rs * DIN + l0 + rc] = pack8(s);
      *(u32x4*)&dst[(size_t)(DD + d0 + c) * K2 + rd * DIN + l0 + rc] = pack8(dl);
    }
  }
}

// ---------------------------------------------------------------------------
// Complex GEMM, ring-buffered counted-vmcnt schedule.
// Block: 128 A-rows x 128 packed-cols. 8 waves (2 row-bands x 4 col-bands),
// wave tile 64 rows x {q0,q1}x16 d. LDS: 4 slice-buffers x 4 arrays x 8 KB.
// Slice = 32 k. Per slice per thread: 4 gl_lds16 (steady in-flight = 12).
// LDS layout per array-slice: [line 0..63][chunk 0..7] 16B slots; line L holds
// rows 2L,2L+1; row r k-chunk kc at logical chunk (r&1)*4+kc, physical chunk
// XOR (line&7). Stage side pre-swizzles the GLOBAL source (rule: both sides).
__global__ __launch_bounds__(512, 2) void cplx_gemm(
    const unsigned short* __restrict__ Ar, const unsigned short* __restrict__ Ai,
    const unsigned short* __restrict__ Br, const unsigned short* __restrict__ Bi,
    const float* __restrict__ bias, float* __restrict__ out) {
  __shared__ u32x4 lds[4][4][512];  // [buf][Ar,Ai,Br,Bi][slot] = 128 KB

  const int tid = threadIdx.x;
  const int wid = tid >> 6;
  const int lane = tid & 63;
  const int lrow = lane & 15;
  const int q4 = lane >> 4;
  const u32x4 nmask = {NEG, NEG, NEG, NEG};

  // XCD-aware bijective swizzle (1024 blocks, 1024%8==0).
  int flat = blockIdx.y * 32 + blockIdx.x;
  flat = (flat & 7) * 128 + (flat >> 3);
  const int tn = flat & 31;
  const int tm = flat >> 5;
  const int d0 = tn * 64;
  const size_t arow0 = (size_t)tm * 128;

  // Staging decode: thread stages slot tid of each array.
  const int sline = tid >> 3;
  const int scl = (tid & 7) ^ (sline & 7);
  const int srow = 2 * sline + (scl >> 2);
  const int skc = scl & 3;
  const unsigned short* gAr = Ar + (arow0 + srow) * (size_t)K2 + skc * 8;
  const unsigned short* gAi = Ai + (arow0 + srow) * (size_t)K2 + skc * 8;
  const size_t offB =
      ((size_t)((srow >> 6) * DD + d0 + (srow & 63))) * K2 + skc * 8;
  const unsigned short* gBr = Br + offB;
  const unsigned short* gBi = Bi + offB;

  // Fragment slot decode (per thread, constant over slices).
  const int wrow = (wid >> 2) * 64;
  const int wc = wid & 3;
  int slotA[4], slotB[2];
#pragma unroll
  for (int mt = 0; mt < 4; ++mt) {
    const int r = wrow + mt * 16 + lrow;
    const int ln = r >> 1;
    const int cl = (r & 1) * 4 + q4;
    slotA[mt] = ln * 8 + (cl ^ (ln & 7));
  }
#pragma unroll
  for (int nt = 0; nt < 2; ++nt) {
    const int r = nt * 64 + wc * 16 + lrow;
    const int ln = r >> 1;
    const int cl = (r & 1) * 4 + q4;
    slotB[nt] = ln * 8 + (cl ^ (ln & 7));
  }

  f32x4 accR[4][2] = {};  // [mt][q]
  f32x4 accI[4][2] = {};

#define STAGE(B3, S3)                                      \
  {                                                        \
    const size_t ko = (size_t)(S3) * 32;                   \
    gl_lds16(gAr + ko, &lds[B3][0][wid * 64]);             \
    gl_lds16(gAi + ko, &lds[B3][1][wid * 64]);             \
    gl_lds16(gBr + ko, &lds[B3][2][wid * 64]);             \
    gl_lds16(gBi + ko, &lds[B3][3][wid * 64]);             \
  }

#define SLICE(BB)                                                         \
  {                                                                       \
    FragU arf[4], aif[4], brf[2], bif[2];                                 \
    _Pragma("unroll") for (int mt = 0; mt < 4; ++mt) {                    \
      arf[mt].u = lds[BB][0][slotA[mt]];                                  \
      aif[mt].u = lds[BB][1][slotA[mt]];                                  \
    }                                                                     \
    _Pragma("unroll") for (int nt = 0; nt < 2; ++nt) {                    \
      brf[nt].u = lds[BB][2][slotB[nt]];                                  \
      bif[nt].u = lds[BB][3][slotB[nt]];                                  \
    }                                                                     \
    asm volatile("s_waitcnt lgkmcnt(0)" ::: "memory");                    \
    __builtin_amdgcn_s_barrier();                                         \
    __builtin_amdgcn_sched_barrier(0);                                    \
    __builtin_amdgcn_s_setprio(1);                                        \
    _Pragma("unroll") for (int mt = 0; mt < 4; ++mt) {                    \
      FragU ain;                                                          \
      ain.u = aif[mt].u ^ nmask;                                          \
      _Pragma("unroll") for (int nt = 0; nt < 2; ++nt) {                  \
        accR[mt][nt] = __builtin_amdgcn_mfma_f32_16x16x32_bf16(           \
            arf[mt].v, brf[nt].v, accR[mt][nt], 0, 0, 0);                 \
        accR[mt][nt] = __builtin_amdgcn_mfma_f32_16x16x32_bf16(           \
            ain.v, bif[nt].v, accR[mt][nt], 0, 0, 0);                     \
        accI[mt][nt] = __builtin_amdgcn_mfma_f32_16x16x32_bf16(           \
            arf[mt].v, bif[nt].v, accI[mt][nt], 0, 0, 0);                 \
        accI[mt][nt] = __builtin_amdgcn_mfma_f32_16x16x32_bf16(           \
            aif[mt].v, brf[nt].v, accI[mt][nt], 0, 0, 0);                 \
      }                                                                   \
    }                                                                     \
    __builtin_amdgcn_s_setprio(0);                                        \
  }

  // Prologue: slices 0,1,2 -> bufs 0,1,2 (12 loads in flight).
  STAGE(0, 0)
  STAGE(1, 1)
  STAGE(2, 2)

  int s3 = 3;
#define ITER(OFF)                                        \
  {                                                      \
    STAGE((OFF + 3) & 3, s3)                             \
    if (++s3 == NSLICE) s3 = 0;                          \
    asm volatile("s_waitcnt vmcnt(12)" ::: "memory");    \
    __builtin_amdgcn_s_barrier();                        \
    __builtin_amdgcn_sched_barrier(0);                   \
    SLICE(OFF)                                           \
  }

  for (int s0 = 0; s0 < NSLICE; s0 += 4) {
    ITER(0)
    ITER(1)
    ITER(2)
    ITER(3)
  }
#undef ITER
#undef SLICE
#undef STAGE

  // Epilogue: thread-local blade decode (identical math to R3).
  // C/D layout: col = lane&15, row = q4*4 + reg (m89-verified).
  const size_t ks = (size_t)BATCH * DD;
  const int d = d0 + wc * 16 + lrow;
  float bv[8];
#pragma unroll
  for (int k = 0; k < 8; ++k) bv[k] = bias[k * DD + d];
#pragma unroll
  for (int mt = 0; mt < 4; ++mt) {
    const int rowbase = tm * 128 + wrow + mt * 16 + q4 * 4;  // even
    const f32x4 R0 = accR[mt][0], R1 = accR[mt][1];
    const f32x4 I0 = accI[mt][0], I1 = accI[mt][1];
#pragma unroll
    for (int j = 0; j < 2; ++j) {
      const int b = (rowbase >> 1) + j;
      const float y00r = R0[2 * j], y10r = R0[2 * j + 1];
      const float y01r = R1[2 * j], y11r = R1[2 * j + 1];
      const float y00i = I0[2 * j], y10i = I0[2 * j + 1];
      const float y01i = I1[2 * j], y11i = I1[2 * j + 1];
      float* o = out + (size_t)b * DD + d;
      o[0]      = (y00r + y11r) + bv[0];  // scalar
      o[ks]     = (y01r + y10r) + bv[1];  // e1
      o[2 * ks] = (y10i - y01i) + bv[2];  // e2
      o[3 * ks] = (y00r - y11r) + bv[3];  // e3
      o[4 * ks] = (y00i - y11i) + bv[4];  // e12
      o[5 * ks] = (y10r - y01r) + bv[5];  // e13
      o[6 * ks] = (y01i + y10i) + bv[6];  // e23
      o[7 * ks] = (y00i + y11i) + bv[7];  // e123
    }
  }
}

extern "C" void kernel_launch(void* const* d_in, const int* in_sizes, int n_in,
                              void* d_out, int out_size, void* d_ws,
                              size_t ws_size, hipStream_t stream) {
  const float* x = (const float*)d_in[0];     // [16384][2048]
  const float* W = (const float*)d_in[1];     // [2048][16384]
  const float* bias = (const float*)d_in[2];  // [16384]
  float* out = (float*)d_out;                 // [16384][2048]

  unsigned short* Arp = (unsigned short*)d_ws;  // 33.5 MB each
  unsigned short* Aip = Arp + (size_t)R2R * K2;
  unsigned short* Brp = Aip + (size_t)R2R * K2;
  unsigned short* Bip = Brp + (size_t)(2 * DD) * K2;  // total 134 MB

  pack_x<<<BATCH, 256, 0, stream>>>(x, Arp, Aip);
  pack_w<<<dim3(DD / 64, DIN / 64, 4), 256, 0, stream>>>(W, Brp, Bip);
  cplx_gemm<<<dim3(32, 32), 512, 0, stream>>>(Arp, Aip, Brp, Bip, bias, out);
}

// Round 3
// 778.379 us; speedup vs baseline: 1.0844x; 1.0844x over previous
//
#include <hip/hip_runtime.h>
#include <hip/hip_bf16.h>
#include <stdint.h>

// R5: R3's verified geometry (128x128 tile, 4 waves of 64x64, XOR-swizzled LDS,
// identical MFMA k-order/epilogue) + prefetch-ahead double buffer with counted
// vmcnt. BK 64->32; Ar|Ai (Br|Bi) share one 8-chunk buffer so dbuf = 64 KB and
// 2 blocks/CU survive. Per K-tile: STAGE(next) -> vmcnt(8) (loads issued one
// full iter earlier; never drained to 0 in-loop) -> s_barrier -> ds_read ->
// lgkmcnt(0) -> s_barrier -> setprio(1) + 64 MFMA. No XCD swizzle (R4's
// doubled FETCH_SIZE). Math bit-identical to R3 (absmax-stable).

#define BATCH 2048
#define DIN 2048
#define DD 2048
#define K2 4096   // 2*DIN
#define R2R 4096  // 2*BATCH
#define NT 128    // K2/32 K-tiles

typedef __attribute__((ext_vector_type(8))) __bf16 bf16x8;
typedef __attribute__((ext_vector_type(4))) float f32x4;
typedef __attribute__((ext_vector_type(4))) unsigned int u32x4;

#define NEG 0x80008000u

__device__ __forceinline__ unsigned short f2bf(float f) {
  unsigned int u = __float_as_uint(f);
  u = (u + 0x7FFFu + ((u >> 16) & 1u)) >> 16;  // RNE
  return (unsigned short)u;
}

__device__ __forceinline__ u32x4 pack8(const float* s) {
  u32x4 p;
#pragma unroll
  for (int w = 0; w < 4; ++w)
    p[w] = (unsigned)f2bf(s[2 * w]) | ((unsigned)f2bf(s[2 * w + 1]) << 16);
  return p;
}

__device__ __forceinline__ void gl_lds16(const void* g, void* l) {
  __builtin_amdgcn_global_load_lds((__attribute__((address_space(1))) void*)g,
                                   (__attribute__((address_space(3))) void*)l,
                                   16, 0, 0);
}

union FragU {
  u32x4 u;
  bf16x8 v;
};

// ---------------------------------------------------------------------------
// pack_x: x [8*B, DIN] fp32 -> Ar, Ai [2B, 2*DIN] bf16.  (unchanged, verified)
//   M11=(x0+x3)+i(x7+x4)  M12=(x1-x5)+i(x6-x2)
//   M21=(x1+x5)+i(x6+x2)  M22=(x0-x3)+i(x7-x4)
__global__ void pack_x(const float* __restrict__ x,
                       unsigned short* __restrict__ Ar,
                       unsigned short* __restrict__ Ai) {
  const int b = blockIdx.x;
  const int l0 = threadIdx.x * 8;
  float v[8][8];
#pragma unroll
  for (int i = 0; i < 8; ++i) {
    const float4* p = (const float4*)&x[((size_t)i * BATCH + b) * DIN + l0];
    float4 a = p[0], c = p[1];
    v[i][0] = a.x; v[i][1] = a.y; v[i][2] = a.z; v[i][3] = a.w;
    v[i][4] = c.x; v[i][5] = c.y; v[i][6] = c.z; v[i][7] = c.w;
  }
  const size_t r0 = (size_t)(2 * b) * K2;
  const size_t r1 = (size_t)(2 * b + 1) * K2;
  float t[8];
#pragma unroll
  for (int e = 0; e < 8; ++e) t[e] = 0.5f * (v[0][e] + v[3][e]);
  *(u32x4*)&Ar[r0 + l0] = pack8(t);
#pragma unroll
  for (int e = 0; e < 8; ++e) t[e] = 0.5f * (v[1][e] - v[5][e]);
  *(u32x4*)&Ar[r0 + DIN + l0] = pack8(t);
#pragma unroll
  for (int e = 0; e < 8; ++e) t[e] = 0.5f * (v[1][e] + v[5][e]);
  *(u32x4*)&Ar[r1 + l0] = pack8(t);
#pragma unroll
  for (int e = 0; e < 8; ++e) t[e] = 0.5f * (v[0][e] - v[3][e]);
  *(u32x4*)&Ar[r1 + DIN + l0] = pack8(t);
#pragma unroll
  for (int e = 0; e < 8; ++e) t[e] = 0.5f * (v[7][e] + v[4][e]);
  *(u32x4*)&Ai[r0 + l0] = pack8(t);
#pragma unroll
  for (int e = 0; e < 8; ++e) t[e] = 0.5f * (v[6][e] - v[2][e]);
  *(u32x4*)&Ai[r0 + DIN + l0] = pack8(t);
#pragma unroll
  for (int e = 0; e < 8; ++e) t[e] = 0.5f * (v[6][e] + v[2][e]);
  *(u32x4*)&Ai[r1 + l0] = pack8(t);
#pragma unroll
  for (int e = 0; e < 8; ++e) t[e] = 0.5f * (v[7][e] - v[4][e]);
  *(u32x4*)&Ai[r1 + DIN + l0] = pack8(t);
}

// ---------------------------------------------------------------------------
// pack_w: W [DIN, 8*DD] fp32 -> Br, Bi [2*DD, 2*DIN] bf16.  (unchanged)
__constant__ int c_pw[4][2] = {{0, 3}, {1, 5}, {7, 4}, {6, 2}};

__global__ void pack_w(const float* __restrict__ W,
                       unsigned short* __restrict__ Br,
                       unsigned short* __restrict__ Bi) {
  __shared__ float ts[64][65], td[64][65];
  const int z = blockIdx.z;
  const int p0 = c_pw[z][0], p1 = c_pw[z][1];
  unsigned short* dst = (z < 2) ? Br : Bi;
  const int rs = z & 1;
  const int rd = rs ^ 1;
  const int d0 = blockIdx.x * 64;
  const int l0 = blockIdx.y * 64;
  const int tid = threadIdx.x;
  {
    const int row = tid >> 4;
    const int col = (tid & 15) * 4;
#pragma unroll
    for (int j = 0; j < 4; ++j) {
      const size_t base = (size_t)(l0 + row + j * 16) * (8 * DD);
      float4 a = *(const float4*)&W[base + (size_t)p0 * DD + d0 + col];
      float4 b = *(const float4*)&W[base + (size_t)p1 * DD + d0 + col];
      ts[row + j * 16][col + 0] = a.x + b.x;
      ts[row + j * 16][col + 1] = a.y + b.y;
      ts[row + j * 16][col + 2] = a.z + b.z;
      ts[row + j * 16][col + 3] = a.w + b.w;
      td[row + j * 16][col + 0] = a.x - b.x;
      td[row + j * 16][col + 1] = a.y - b.y;
      td[row + j * 16][col + 2] = a.z - b.z;
      td[row + j * 16][col + 3] = a.w - b.w;
    }
  }
  __syncthreads();
  {
    const int rc = (tid & 7) * 8;
    int c = tid >> 3;
#pragma unroll
    for (int h = 0; h < 2; ++h, c += 32) {
      float s[8], dl[8];
#pragma unroll
      for (int w = 0; w < 8; ++w) {
        s[w] = ts[rc + w][c];
        dl[w] = td[rc + w][c];
      }
      *(u32x4*)&dst[(size_t)(d0 + c) * K2 + rs * DIN + l0 + rc] = pack8(s);
      *(u32x4*)&dst[(size_t)(DD + d0 + c) * K2 + rd * DIN + l0 + rc] = pack8(dl);
    }
  }
}

// ---------------------------------------------------------------------------
// Complex GEMM, double-buffered prefetch-ahead schedule.
// Block 128 rows x 128 packed cols, 4 waves (2x2), wave 64x64, BK=32.
// LDS per buffer: AC[1024] slots (128 rows x 8 chunks: 0-3=Ar k-chunks,
// 4-7=Ai) + BC[1024] same for Br|Bi. Physical chunk = logical ^ (row&7)
// via pre-swizzled GLOBAL source (both-sides rule); dbuf = 64 KB total.
__global__ __launch_bounds__(256, 2) void cplx_gemm(
    const unsigned short* __restrict__ Ar, const unsigned short* __restrict__ Br,
    const float* __restrict__ bias, float* __restrict__ out) {
  __shared__ u32x4 AC[2][1024];  // 32 KB
  __shared__ u32x4 BC[2][1024];  // 32 KB

  const int tid = threadIdx.x;
  const int wid = tid >> 6;
  const int lane = tid & 63;
  const int lrow = lane & 15;
  const int q4 = lane >> 4;
  const int wr = wid & 1;
  const int wc = wid >> 1;
  const u32x4 nmask = {NEG, NEG, NEG, NEG};

  const int tn = blockIdx.x;
  const int tm = blockIdx.y;
  const int d0 = tn * 64;
  const size_t arow0 = (size_t)tm * 128;

  // Staging decode: thread stages slots L = t*256+tid of AC and BC.
  // Logical chunk c = (L&7)^(m&7); c<4 -> real array k-chunk c, c>=4 -> imag.
  // Ar/Ai and Br/Bi are contiguous in workspace -> 32-bit elem offsets.
  unsigned int aoff[4], boff[4];
#pragma unroll
  for (int t = 0; t < 4; ++t) {
    const int L = t * 256 + tid;
    const int m = L >> 3;
    const int c = (L & 7) ^ (m & 7);
    const unsigned int imag = (c >> 2) ? (unsigned int)R2R * K2 : 0u;
    aoff[t] = imag + (unsigned int)(arow0 + m) * K2 + (c & 3) * 8;
    const unsigned int brow = (m >> 6) * DD + d0 + (m & 63);
    boff[t] = imag + brow * (unsigned int)K2 + (c & 3) * 8;
  }

  // Fragment slots (constant per thread). slot^4 flips real<->imag chunk.
  int slotA[4], slotB[4];
#pragma unroll
  for (int mt = 0; mt < 4; ++mt) {
    const int r = wr * 64 + mt * 16 + lrow;
    slotA[mt] = r * 8 + (q4 ^ (r & 7));
  }
#pragma unroll
  for (int nt = 0; nt < 4; ++nt) {
    const int r = (nt >> 1) * 64 + wc * 32 + (nt & 1) * 16 + lrow;
    slotB[nt] = r * 8 + (q4 ^ (r & 7));
  }

  f32x4 accR[4][4] = {};
  f32x4 accI[4][4] = {};

#define STAGE(BUF, KT)                                          \
  {                                                             \
    const unsigned int ko = (unsigned int)(KT) * 32u;           \
    _Pragma("unroll") for (int t = 0; t < 4; ++t) {             \
      gl_lds16(Ar + aoff[t] + ko, &AC[BUF][t * 256 + wid * 64]);\
      gl_lds16(Br + boff[t] + ko, &BC[BUF][t * 256 + wid * 64]);\
    }                                                           \
  }

#define COMPUTE(BUF)                                                      \
  {                                                                       \
    FragU arf[4], aif[4], brf[4], bif[4];                                 \
    _Pragma("unroll") for (int mt = 0; mt < 4; ++mt) {                    \
      arf[mt].u = AC[BUF][slotA[mt]];                                     \
      aif[mt].u = AC[BUF][slotA[mt] ^ 4];                                 \
    }                                                                     \
    _Pragma("unroll") for (int nt = 0; nt < 4; ++nt) {                    \
      brf[nt].u = BC[BUF][slotB[nt]];                                     \
      bif[nt].u = BC[BUF][slotB[nt] ^ 4];                                 \
    }                                                                     \
    asm volatile("s_waitcnt lgkmcnt(0)" ::: "memory");                    \
    __builtin_amdgcn_s_barrier(); /* all reads done -> next STAGE safe */ \
    __builtin_amdgcn_sched_barrier(0);                                    \
    __builtin_amdgcn_s_setprio(1);                                        \
    _Pragma("unroll") for (int mt = 0; mt < 4; ++mt) {                    \
      FragU ain;                                                          \
      ain.u = aif[mt].u ^ nmask;                                          \
      _Pragma("unroll") for (int nt = 0; nt < 4; ++nt) {                  \
        accR[mt][nt] = __builtin_amdgcn_mfma_f32_16x16x32_bf16(           \
            arf[mt].v, brf[nt].v, accR[mt][nt], 0, 0, 0);                 \
        accR[mt][nt] = __builtin_amdgcn_mfma_f32_16x16x32_bf16(           \
            ain.v, bif[nt].v, accR[mt][nt], 0, 0, 0);                     \
        accI[mt][nt] = __builtin_amdgcn_mfma_f32_16x16x32_bf16(           \
            arf[mt].v, bif[nt].v, accI[mt][nt], 0, 0, 0);                 \
        accI[mt][nt] = __builtin_amdgcn_mfma_f32_16x16x32_bf16(           \
            aif[mt].v, brf[nt].v, accI[mt][nt], 0, 0, 0);                 \
      }                                                                   \
    }                                                                     \
    __builtin_amdgcn_s_setprio(0);                                        \
  }

// One pipelined iteration: stage tile KT into BUF^1, wait for BUF's loads
// (issued one full iteration earlier -> near-zero stall), compute BUF.
#define ITER(BUF, KT)                                     \
  {                                                       \
    STAGE(BUF ^ 1, KT)                                    \
    asm volatile("s_waitcnt vmcnt(8)" ::: "memory");      \
    __builtin_amdgcn_s_barrier();                         \
    __builtin_amdgcn_sched_barrier(0);                    \
    COMPUTE(BUF)                                          \
  }

  STAGE(0, 0)
  int kt = 1;
  for (int pair = 0; pair < 63; ++pair) {
    ITER(0, kt) ++kt;
    ITER(1, kt) ++kt;
  }
  ITER(0, 127)  // stages tile 127 into buf1, computes tile 126 (buf0)
  // Final tile: drain and compute buf1.
  asm volatile("s_waitcnt vmcnt(0)" ::: "memory");
  __builtin_amdgcn_s_barrier();
  __builtin_amdgcn_sched_barrier(0);
  COMPUTE(1)
#undef ITER
#undef COMPUTE
#undef STAGE

  // Epilogue: thread-local blade decode (identical to R3, m89-verified C/D).
  const size_t ks = (size_t)BATCH * DD;
#pragma unroll
  for (int ntd = 0; ntd < 2; ++ntd) {
    const int d = d0 + wc * 32 + ntd * 16 + lrow;
    float bv[8];
#pragma unroll
    for (int k = 0; k < 8; ++k) bv[k] = bias[k * DD + d];
#pragma unroll
    for (int mt = 0; mt < 4; ++mt) {
      const int rowbase = tm * 128 + wr * 64 + mt * 16 + q4 * 4;  // even
      const f32x4 R0 = accR[mt][ntd], R1 = accR[mt][2 + ntd];
      const f32x4 I0 = accI[mt][ntd], I1 = accI[mt][2 + ntd];
#pragma unroll
      for (int j = 0; j < 2; ++j) {
        const int b = (rowbase >> 1) + j;
        const float y00r = R0[2 * j], y10r = R0[2 * j + 1];
        const float y01r = R1[2 * j], y11r = R1[2 * j + 1];
        const float y00i = I0[2 * j], y10i = I0[2 * j + 1];
        const float y01i = I1[2 * j], y11i = I1[2 * j + 1];
        float* o = out + (size_t)b * DD + d;
        o[0]      = (y00r + y11r) + bv[0];  // scalar
        o[ks]     = (y01r + y10r) + bv[1];  // e1
        o[2 * ks] = (y10i - y01i) + bv[2];  // e2
        o[3 * ks] = (y00r - y11r) + bv[3];  // e3
        o[4 * ks] = (y00i - y11i) + bv[4];  // e12
        o[5 * ks] = (y10r - y01r) + bv[5];  // e13
        o[6 * ks] = (y01i + y10i) + bv[6];  // e23
        o[7 * ks] = (y00i + y11i) + bv[7];  // e123
      }
    }
  }
}

extern "C" void kernel_launch(void* const* d_in, const int* in_sizes, int n_in,
                              void* d_out, int out_size, void* d_ws,
                              size_t ws_size, hipStream_t stream) {
  const float* x = (const float*)d_in[0];     // [16384][2048]
  const float* W = (const float*)d_in[1];     // [2048][16384]
  const float* bias = (const float*)d_in[2];  // [16384]
  float* out = (float*)d_out;                 // [16384][2048]

  unsigned short* Arp = (unsigned short*)d_ws;  // Ar|Ai|Br|Bi, 33.5 MB each
  unsigned short* Aip = Arp + (size_t)R2R * K2;
  unsigned short* Brp = Aip + (size_t)R2R * K2;
  unsigned short* Bip = Brp + (size_t)(2 * DD) * K2;  // total 134 MB

  pack_x<<<BATCH, 256, 0, stream>>>(x, Arp, Aip);
  pack_w<<<dim3(DD / 64, DIN / 64, 4), 256, 0, stream>>>(W, Brp, Bip);
  cplx_gemm<<<dim3(32, 32), 256, 0, stream>>>(Arp, Brp, bias, out);
}

// Round 5
// 712.690 us; speedup vs baseline: 1.1843x; 1.0922x over previous
//
#include <hip/hip_runtime.h>
#include <hip/hip_bf16.h>
#include <stdint.h>

// R6b: identical resubmission of R6 (previous bench failed on container
// acquisition, not on the kernel). cplx_gemm is byte-for-byte R3 (measured
// 430 µs, MfmaUtil 57%, FETCH 611 MB — both pipelined variants R4/R5
// regressed by doubling L2-miss traffic: the per-tile drain K-phase-locks
// co-resident blocks and preserves L2 slice reuse). pack_w: (bf16(sum),
// bf16(diff)) packed per-u32 in LDS -> half the LDS bytes/ops, 17 KB
// footprint, pad 65 (2-way conflicts only). pack_x unchanged.

#define BATCH 2048
#define DIN 2048
#define DD 2048
#define K2 4096   // 2*DIN
#define R2R 4096  // 2*BATCH

typedef __attribute__((ext_vector_type(8))) __bf16 bf16x8;
typedef __attribute__((ext_vector_type(4))) float f32x4;
typedef __attribute__((ext_vector_type(4))) unsigned int u32x4;

#define NEG 0x80008000u

__device__ __forceinline__ unsigned short f2bf(float f) {
  unsigned int u = __float_as_uint(f);
  u = (u + 0x7FFFu + ((u >> 16) & 1u)) >> 16;  // RNE
  return (unsigned short)u;
}

__device__ __forceinline__ u32x4 pack8(const float* s) {
  u32x4 p;
#pragma unroll
  for (int w = 0; w < 4; ++w)
    p[w] = (unsigned)f2bf(s[2 * w]) | ((unsigned)f2bf(s[2 * w + 1]) << 16);
  return p;
}

__device__ __forceinline__ void gl_lds16(const void* g, void* l) {
  __builtin_amdgcn_global_load_lds((__attribute__((address_space(1))) void*)g,
                                   (__attribute__((address_space(3))) void*)l,
                                   16, 0, 0);
}

union FragU {
  u32x4 u;
  bf16x8 v;
};

// ---------------------------------------------------------------------------
// pack_x: x [8*B, DIN] fp32 -> Ar, Ai [2B, 2*DIN] bf16.  (verified, unchanged)
//   M11=(x0+x3)+i(x7+x4)  M12=(x1-x5)+i(x6-x2)
//   M21=(x1+x5)+i(x6+x2)  M22=(x0-x3)+i(x7-x4)
// Global 1/2 of the inverse transform folded here (exact exponent shift).
__global__ void pack_x(const float* __restrict__ x,
                       unsigned short* __restrict__ Ar,
                       unsigned short* __restrict__ Ai) {
  const int b = blockIdx.x;
  const int l0 = threadIdx.x * 8;
  float v[8][8];
#pragma unroll
  for (int i = 0; i < 8; ++i) {
    const float4* p = (const float4*)&x[((size_t)i * BATCH + b) * DIN + l0];
    float4 a = p[0], c = p[1];
    v[i][0] = a.x; v[i][1] = a.y; v[i][2] = a.z; v[i][3] = a.w;
    v[i][4] = c.x; v[i][5] = c.y; v[i][6] = c.z; v[i][7] = c.w;
  }
  const size_t r0 = (size_t)(2 * b) * K2;
  const size_t r1 = (size_t)(2 * b + 1) * K2;
  float t[8];
#pragma unroll
  for (int e = 0; e < 8; ++e) t[e] = 0.5f * (v[0][e] + v[3][e]);
  *(u32x4*)&Ar[r0 + l0] = pack8(t);
#pragma unroll
  for (int e = 0; e < 8; ++e) t[e] = 0.5f * (v[1][e] - v[5][e]);
  *(u32x4*)&Ar[r0 + DIN + l0] = pack8(t);
#pragma unroll
  for (int e = 0; e < 8; ++e) t[e] = 0.5f * (v[1][e] + v[5][e]);
  *(u32x4*)&Ar[r1 + l0] = pack8(t);
#pragma unroll
  for (int e = 0; e < 8; ++e) t[e] = 0.5f * (v[0][e] - v[3][e]);
  *(u32x4*)&Ar[r1 + DIN + l0] = pack8(t);
#pragma unroll
  for (int e = 0; e < 8; ++e) t[e] = 0.5f * (v[7][e] + v[4][e]);
  *(u32x4*)&Ai[r0 + l0] = pack8(t);
#pragma unroll
  for (int e = 0; e < 8; ++e) t[e] = 0.5f * (v[6][e] - v[2][e]);
  *(u32x4*)&Ai[r0 + DIN + l0] = pack8(t);
#pragma unroll
  for (int e = 0; e < 8; ++e) t[e] = 0.5f * (v[6][e] + v[2][e]);
  *(u32x4*)&Ai[r1 + l0] = pack8(t);
#pragma unroll
  for (int e = 0; e < 8; ++e) t[e] = 0.5f * (v[7][e] - v[4][e]);
  *(u32x4*)&Ai[r1 + DIN + l0] = pack8(t);
}

// ---------------------------------------------------------------------------
// pack_w: W [DIN, 8*DD] fp32 -> Br, Bi [2*DD, 2*DIN] bf16 (transposed).
// R6: sum/diff converted to bf16 BEFORE LDS, packed (lo=sum, hi=diff) per u32.
// LDS 64x65 u32 = 17 KB (was 33 KB fp32 x2); half the LDS ops. Pad 65 keeps the
// transpose-read at 2-way bank aliasing (free); float4-able pad 68 would be
// 8-way, so scalar u32 LDS ops are the right trade.
__constant__ int c_pw[4][2] = {{0, 3}, {1, 5}, {7, 4}, {6, 2}};

__global__ void pack_w(const float* __restrict__ W,
                       unsigned short* __restrict__ Br,
                       unsigned short* __restrict__ Bi) {
  __shared__ unsigned int tl[64][65];
  const int z = blockIdx.z;
  const int p0 = c_pw[z][0], p1 = c_pw[z][1];
  unsigned short* dst = (z < 2) ? Br : Bi;
  const int rs = z & 1;   // sum col-region (r)
  const int rd = rs ^ 1;  // diff col-region
  const int d0 = blockIdx.x * 64;
  const int l0 = blockIdx.y * 64;
  const int tid = threadIdx.x;
  {
    const int row = tid >> 4;        // l-local (+16j)
    const int col = (tid & 15) * 4;  // d-local
#pragma unroll
    for (int j = 0; j < 4; ++j) {
      const size_t base = (size_t)(l0 + row + j * 16) * (8 * DD);
      float4 a = *(const float4*)&W[base + (size_t)p0 * DD + d0 + col];
      float4 b = *(const float4*)&W[base + (size_t)p1 * DD + d0 + col];
      tl[row + j * 16][col + 0] =
          (unsigned)f2bf(a.x + b.x) | ((unsigned)f2bf(a.x - b.x) << 16);
      tl[row + j * 16][col + 1] =
          (unsigned)f2bf(a.y + b.y) | ((unsigned)f2bf(a.y - b.y) << 16);
      tl[row + j * 16][col + 2] =
          (unsigned)f2bf(a.z + b.z) | ((unsigned)f2bf(a.z - b.z) << 16);
      tl[row + j * 16][col + 3] =
          (unsigned)f2bf(a.w + b.w) | ((unsigned)f2bf(a.w - b.w) << 16);
    }
  }
  __syncthreads();
  {
    const int rc = (tid & 7) * 8;  // l-chunk of 8
    int c = tid >> 3;              // d-local 0..31, then +32
#pragma unroll
    for (int h = 0; h < 2; ++h, c += 32) {
      unsigned int t[8];
#pragma unroll
      for (int w = 0; w < 8; ++w) t[w] = tl[rc + w][c];
      u32x4 ps, pd;
#pragma unroll
      for (int w = 0; w < 4; ++w) {
        ps[w] = (t[2 * w] & 0xFFFFu) | (t[2 * w + 1] << 16);
        pd[w] = (t[2 * w] >> 16) | (t[2 * w + 1] & 0xFFFF0000u);
      }
      *(u32x4*)&dst[(size_t)(d0 + c) * K2 + rs * DIN + l0 + rc] = ps;
      *(u32x4*)&dst[(size_t)(DD + d0 + c) * K2 + rd * DIN + l0 + rc] = pd;
    }
  }
}

// ---------------------------------------------------------------------------
// Complex GEMM — EXACT R3 (measured 430 µs). Block 128 rows x 128 packed cols,
// 4 waves 2x2, wave 64x64, BK=64, single-buffered 64 KB LDS, XOR-swizzled via
// pre-swizzled global source. Per-tile vmcnt(0) drain at __syncthreads
// K-phase-locks co-resident blocks -> L2 slice reuse (FETCH 611 MB).
__global__ __launch_bounds__(256, 2) void cplx_gemm(
    const unsigned short* __restrict__ Ar, const unsigned short* __restrict__ Ai,
    const unsigned short* __restrict__ Br, const unsigned short* __restrict__ Bi,
    const float* __restrict__ bias, float* __restrict__ out) {
  __shared__ u32x4 ldsAr[1024], ldsAi[1024], ldsBr[1024], ldsBi[1024];  // 64 KB

  const int tid = threadIdx.x;
  const int tn = blockIdx.x;  // d-tile (64 d each)
  const int tm = blockIdx.y;  // row-tile (128 rows each)
  const int wid = tid >> 6;
  const int lane = tid & 63;
  const int wr = wid & 1;
  const int wc = wid >> 1;
  const int lrow = lane & 15;
  const int q4 = lane >> 4;
  const int l7 = lane & 7;
  const u32x4 nmask = {NEG, NEG, NEG, NEG};

  f32x4 accR[4][4] = {};  // [mt][nt], nt = q*2 + ntd
  f32x4 accI[4][4] = {};

  const size_t arow0 = (size_t)tm * 128;
  const int d0 = tn * 64;

  for (int k0 = 0; k0 < K2; k0 += 64) {
    // Stage 4 x 1024 chunks, 4 insts/thread each. Slot L holds logical chunk
    // (L&7)^((L>>3)&7) of row L>>3 (XOR swizzle on the GLOBAL source address).
#pragma unroll
    for (int t = 0; t < 4; ++t) {
      const int L = (t * 4 + wid) * 64 + lane;
      const int m = L >> 3;
      const int c = (L & 7) ^ (m & 7);
      const size_t ao = (arow0 + m) * K2 + (k0 + c * 8);
      gl_lds16(Ar + ao, &ldsAr[(t * 4 + wid) * 64]);
      gl_lds16(Ai + ao, &ldsAi[(t * 4 + wid) * 64]);
      // ldsB rows 0..63 <- Bt rows d0..d0+63 (q=0); rows 64..127 <- DD+d0.. (q=1)
      const size_t bo = ((size_t)((m >> 6) * DD + d0 + (m & 63))) * K2 + (k0 + c * 8);
      gl_lds16(Br + bo, &ldsBr[(t * 4 + wid) * 64]);
      gl_lds16(Bi + bo, &ldsBi[(t * 4 + wid) * 64]);
    }
    __syncthreads();

#pragma unroll
    for (int kk = 0; kk < 2; ++kk) {
      const int p = (kk * 4 + q4) ^ l7;
      FragU arf[4], aif[4], brf[4], bif[4];
#pragma unroll
      for (int mt = 0; mt < 4; ++mt) {
        const int ml = wr * 64 + mt * 16 + lrow;
        arf[mt].u = ldsAr[ml * 8 + p];
        aif[mt].u = ldsAi[ml * 8 + p];
      }
#pragma unroll
      for (int nt = 0; nt < 4; ++nt) {
        const int nl = (nt >> 1) * 64 + wc * 32 + (nt & 1) * 16 + lrow;
        brf[nt].u = ldsBr[nl * 8 + p];
        bif[nt].u = ldsBi[nl * 8 + p];
      }
#pragma unroll
      for (int mt = 0; mt < 4; ++mt) {
        FragU ain;
        ain.u = aif[mt].u ^ nmask;  // -Ai for the Cr path
#pragma unroll
        for (int nt = 0; nt < 4; ++nt) {
          accR[mt][nt] = __builtin_amdgcn_mfma_f32_16x16x32_bf16(
              arf[mt].v, brf[nt].v, accR[mt][nt], 0, 0, 0);
          accR[mt][nt] = __builtin_amdgcn_mfma_f32_16x16x32_bf16(
              ain.v, bif[nt].v, accR[mt][nt], 0, 0, 0);
          accI[mt][nt] = __builtin_amdgcn_mfma_f32_16x16x32_bf16(
              arf[mt].v, bif[nt].v, accI[mt][nt], 0, 0, 0);
          accI[mt][nt] = __builtin_amdgcn_mfma_f32_16x16x32_bf16(
              aif[mt].v, brf[nt].v, accI[mt][nt], 0, 0, 0);
        }
      }
    }
    __syncthreads();
  }

  // Epilogue: thread-local blade decode. C/D layout col=lane&15, row=q4*4+reg.
  // Rows pair (2b,2b+1) = adjacent regs; q pairs = nt vs nt+2 of same thread.
  // 1/2 already folded into pack_x.
  const size_t ks = (size_t)BATCH * DD;
#pragma unroll
  for (int ntd = 0; ntd < 2; ++ntd) {
    const int d = d0 + wc * 32 + ntd * 16 + lrow;
    float bv[8];
#pragma unroll
    for (int k = 0; k < 8; ++k) bv[k] = bias[k * DD + d];
#pragma unroll
    for (int mt = 0; mt < 4; ++mt) {
      const int rowbase = tm * 128 + wr * 64 + mt * 16 + q4 * 4;  // even
      const f32x4 R0 = accR[mt][ntd], R1 = accR[mt][2 + ntd];
      const f32x4 I0 = accI[mt][ntd], I1 = accI[mt][2 + ntd];
#pragma unroll
      for (int j = 0; j < 2; ++j) {
        const int b = (rowbase >> 1) + j;
        const float y00r = R0[2 * j], y10r = R0[2 * j + 1];
        const float y01r = R1[2 * j], y11r = R1[2 * j + 1];
        const float y00i = I0[2 * j], y10i = I0[2 * j + 1];
        const float y01i = I1[2 * j], y11i = I1[2 * j + 1];
        float* o = out + (size_t)b * DD + d;
        o[0]      = (y00r + y11r) + bv[0];  // scalar
        o[ks]     = (y01r + y10r) + bv[1];  // e1
        o[2 * ks] = (y10i - y01i) + bv[2];  // e2
        o[3 * ks] = (y00r - y11r) + bv[3];  // e3
        o[4 * ks] = (y00i - y11i) + bv[4];  // e12
        o[5 * ks] = (y10r - y01r) + bv[5];  // e13
        o[6 * ks] = (y01i + y10i) + bv[6];  // e23
        o[7 * ks] = (y00i + y11i) + bv[7];  // e123
      }
    }
  }
}

extern "C" void kernel_launch(void* const* d_in, const int* in_sizes, int n_in,
                              void* d_out, int out_size, void* d_ws,
                              size_t ws_size, hipStream_t stream) {
  const float* x = (const float*)d_in[0];     // [16384][2048]
  const float* W = (const float*)d_in[1];     // [2048][16384]
  const float* bias = (const float*)d_in[2];  // [16384]
  float* out = (float*)d_out;                 // [16384][2048]

  unsigned short* Arp = (unsigned short*)d_ws;  // 33.5 MB each
  unsigned short* Aip = Arp + (size_t)R2R * K2;
  unsigned short* Brp = Aip + (size_t)R2R * K2;
  unsigned short* Bip = Brp + (size_t)(2 * DD) * K2;  // total 134 MB

  pack_x<<<BATCH, 256, 0, stream>>>(x, Arp, Aip);
  pack_w<<<dim3(DD / 64, DIN / 64, 4), 256, 0, stream>>>(W, Brp, Bip);
  cplx_gemm<<<dim3(32, 32), 256, 0, stream>>>(Arp, Aip, Brp, Bip, bias, out);
}